// Round 4
// baseline (375.990 us; speedup 1.0000x reference)
//
#include <hip/hip_runtime.h>
#include <stdint.h>

#define SEQ   2048
#define DIM   1024
#define BATCH 4

typedef _Float16 f16;
typedef __attribute__((ext_vector_type(8))) _Float16 f16x8;
typedef __attribute__((ext_vector_type(4))) _Float16 f16x4;
typedef __attribute__((ext_vector_type(4))) float   f32x4;

typedef void __attribute__((address_space(1))) vg_t;
typedef void __attribute__((address_space(3))) vl_t;

__device__ __forceinline__ void gld16(const void* g, void* l) {
  // async global->LDS, 16B per lane; LDS dest = wave-uniform base + lane*16
  __builtin_amdgcn_global_load_lds((vg_t*)g, (vl_t*)l, 16, 0, 0);
}

// ---------------------------------------------------------------------------
// Fused fp32->fp16 convert of x, Wq, Wk, Wv in ONE dispatch.
// ---------------------------------------------------------------------------
__global__ __launch_bounds__(256) void cvt_all(const float* __restrict__ x,
                                               const float* __restrict__ wq,
                                               const float* __restrict__ wk,
                                               const float* __restrict__ wv,
                                               f16* __restrict__ xb,
                                               f16* __restrict__ wh) {
  const int bx = blockIdx.x;
  const float* in; f16* out; int base;
  if (bx < 8192)       { in = x;  out = xb;             base = bx; }
  else if (bx < 9216)  { in = wq; out = wh;             base = bx - 8192; }
  else if (bx < 10240) { in = wk; out = wh + (1 << 20); base = bx - 9216; }
  else                 { in = wv; out = wh + (2 << 20); base = bx - 10240; }
  const long i = ((long)base * 256 + threadIdx.x) * 4;
  float4 v = *(const float4*)(in + i);
  f16x4 o = { (f16)v.x, (f16)v.y, (f16)v.z, (f16)v.w };
  *(f16x4*)(out + i) = o;
}

// ---------------------------------------------------------------------------
// NT GEMM, A staged via LDS (double-buffered, 1 barrier/K-step),
// B loaded DIRECTLY from global (L2-resident) as 16B fragments — the NT
// B-fragment B[n=lane&15][k=(lane>>4)*8+j] is 16 contiguous bytes/lane, so
// it needs no LDS round-trip. Removes B from the LDS pipe (96->48 KB per
// block-K-step) and from the barrier drain; B loads pipeline by dependence
// (AITER-style buffer_load<->MFMA interleave).
// C[m,n] = sum_k A[m,k]*B[n,k], fp16 in, fp32 acc. 128x128 tile, BK=64,
// 4 waves (2x2 of 64x64), 16x16x32 MFMA. LDS = 2 x 16 KB (A only).
// MODE: 0 fp32 row-major C | 1 f16 row-major C | 2 f16 transposed C |
//       3 fused QKV routing (Q,K row-major + V transposed)
// CAUSAL: 0 none | 1 skip tiles above diagonal | 2 K-limit m0+128 (PV)
// XOR chunk swizzle on A: LDS slot (row, j) holds global chunk j ^ (row&7).
// ---------------------------------------------------------------------------
template <int MODE, int CAUSAL>
__global__ __launch_bounds__(256) void gemm_bt(const f16* __restrict__ A, int lda, long aOffZ,
                                               const f16* __restrict__ B, int ldb, long bOffZ,
                                               void* __restrict__ Cv, int ldc, long cOffZ,
                                               int K) {
  constexpr int BK = 64;
  __shared__ __align__(16) f16 lA[2][128 * BK];

  const int tid  = threadIdx.x;
  const int wave = tid >> 6;
  const int lane = tid & 63;
  const int m0 = blockIdx.x * 128;
  const int n0 = blockIdx.y * 128;
  const int z  = blockIdx.z;

  if (CAUSAL == 1 && n0 >= m0 + 128) return;
  const int Keff = (CAUSAL == 2) ? (m0 + 128) : K;

  const f16* Ab = A + (long)z * aOffZ + (long)m0 * lda;
  const f16* Bb = B + (long)z * bOffZ + (long)n0 * ldb;

  const int wm = (wave & 1) * 64;
  const int wn = (wave >> 1) * 64;

  f32x4 acc[4][4] = {};

  const int srow = lane >> 3;   // staging: row within 8-row group
  const int sj   = lane & 7;    // staging: 16B chunk in row
  const int fr   = lane & 15;   // fragment row
  const int fq   = lane >> 4;   // fragment quad

  // per-lane B row pointers (n = n0 + wn + i*16 + fr), fragment = ptr + k + fq*8
  const f16* Brow[4];
#pragma unroll
  for (int i = 0; i < 4; ++i) Brow[i] = Bb + (long)(wn + i * 16 + fr) * ldb + fq * 8;

  // issue A-tile global->LDS loads into buffer `buf` (4 insts/lane, 16 KB)
  auto stage = [&](int buf, int kt) {
#pragma unroll
    for (int j = 0; j < 4; ++j) {
      const int rgrp = j * 4 + wave;
      const int row  = rgrp * 8 + srow;
      const int gch  = sj ^ (row & 7);
      gld16(Ab + (long)row * lda + kt + gch * 8, (void*)(&lA[buf][rgrp * 512 + lane * 8]));
    }
  };

  // MFMA over one staged A-tile; B fragments direct from global at kt
  auto compute = [&](int buf, int kt) {
#pragma unroll
    for (int kk = 0; kk < BK; kk += 32) {
      f16x8 af[4], bf[4];
#pragma unroll
      for (int i = 0; i < 4; ++i) {
        const int arow = wm + i * 16 + fr;
        const int ach  = (kk / 8 + fq) ^ (arow & 7);
        af[i] = *(const f16x8*)(&lA[buf][arow * BK + ach * 8]);
        bf[i] = *(const f16x8*)(Brow[i] + kt + kk);
      }
#pragma unroll
      for (int mi = 0; mi < 4; ++mi)
#pragma unroll
        for (int ni = 0; ni < 4; ++ni)
          acc[mi][ni] = __builtin_amdgcn_mfma_f32_16x16x32_f16(af[mi], bf[ni], acc[mi][ni], 0, 0, 0);
    }
  };

  stage(0, 0);
  for (int kt = 0; kt < Keff; kt += 2 * BK) {
    __syncthreads();                                 // buf0 A ready (1 compute phase in flight)
    if (kt + BK < Keff) stage(1, kt + BK);
    compute(0, kt);
    if (kt + BK < Keff) {
      __syncthreads();                               // buf1 A ready
      if (kt + 2 * BK < Keff) stage(0, kt + 2 * BK);
      compute(1, kt + BK);
    }
  }

  // Epilogue. C/D layout: col = lane&15, row = (lane>>4)*4 + reg
#pragma unroll
  for (int mi = 0; mi < 4; ++mi) {
    const int row = m0 + wm + mi * 16 + fq * 4;
#pragma unroll
    for (int ni = 0; ni < 4; ++ni) {
      const int col = n0 + wn + ni * 16 + fr;
      if constexpr (MODE == 0) {
        float* C = (float*)Cv + (long)z * cOffZ;
#pragma unroll
        for (int r = 0; r < 4; ++r) C[(long)(row + r) * ldc + col] = acc[mi][ni][r];
      } else if constexpr (MODE == 1) {
        f16* C = (f16*)Cv + (long)z * cOffZ;
#pragma unroll
        for (int r = 0; r < 4; ++r) C[(long)(row + r) * ldc + col] = (f16)acc[mi][ni][r];
      } else if constexpr (MODE == 2) {
        f16* C = (f16*)Cv + (long)z * cOffZ;
        f16x4 o = { (f16)acc[mi][ni][0], (f16)acc[mi][ni][1],
                    (f16)acc[mi][ni][2], (f16)acc[mi][ni][3] };
        *(f16x4*)(C + (long)col * ldc + row) = o;
      } else {  // MODE 3: fused QKV routing (wave-uniform; tiles don't straddle 1024-boundaries)
        f16* Qh  = (f16*)Cv;
        f16* Kh  = Qh + (size_t)8 * 1024 * 1024;
        f16* VTb = Kh + (size_t)8 * 1024 * 1024;
        if (col < 1024) {
#pragma unroll
          for (int r = 0; r < 4; ++r) Qh[(long)(row + r) * DIM + col] = (f16)acc[mi][ni][r];
        } else if (col < 2048) {
#pragma unroll
          for (int r = 0; r < 4; ++r) Kh[(long)(row + r) * DIM + (col - 1024)] = (f16)acc[mi][ni][r];
        } else {
          f16x4 o = { (f16)acc[mi][ni][0], (f16)acc[mi][ni][1],
                      (f16)acc[mi][ni][2], (f16)acc[mi][ni][3] };
          *(f16x4*)(VTb + (long)(col - 2048) * (BATCH * SEQ) + row) = o;
        }
      }
    }
  }
}

// ---------------------------------------------------------------------------
// Causal softmax over f16 score rows, in-place (zero above diagonal).
// grid = (SEQ, BATCH), block = 256, 8 contiguous elems/thread (f16x8).
// ---------------------------------------------------------------------------
__global__ __launch_bounds__(256) void softmax_causal(f16* S) {
  const int q = blockIdx.x, b = blockIdx.y;
  f16* row = S + ((long)b * SEQ + q) * SEQ;
  const int tid = threadIdx.x;
  const int lane = tid & 63, wave = tid >> 6;
  const int nvalid = q + 1;

  f16x8 vv = *(const f16x8*)(row + tid * 8);
  float v[8];
  float m = -3.0e38f;
#pragma unroll
  for (int i = 0; i < 8; ++i) {
    const int k = tid * 8 + i;
    v[i] = (k < nvalid) ? (float)vv[i] * 0.03125f : -3.0e38f;
    m = fmaxf(m, v[i]);
  }
#pragma unroll
  for (int off = 32; off; off >>= 1) m = fmaxf(m, __shfl_xor(m, off));
  __shared__ float redm[4], reds[4];
  if (lane == 0) redm[wave] = m;
  __syncthreads();  // all reads of `row` complete before this point
  m = fmaxf(fmaxf(redm[0], redm[1]), fmaxf(redm[2], redm[3]));

  float s = 0.f;
#pragma unroll
  for (int i = 0; i < 8; ++i) {
    const float p = (v[i] > -1.0e37f) ? __expf(v[i] - m) : 0.f;
    v[i] = p;
    s += p;
  }
#pragma unroll
  for (int off = 32; off; off >>= 1) s += __shfl_xor(s, off);
  if (lane == 0) reds[wave] = s;
  __syncthreads();
  s = reds[0] + reds[1] + reds[2] + reds[3];
  const float inv = 1.f / s;
  f16x8 o;
#pragma unroll
  for (int i = 0; i < 8; ++i) o[i] = (f16)(v[i] * inv);
  *(f16x8*)(row + tid * 8) = o;  // after barriers -> no overlap hazard
}

// ---------------------------------------------------------------------------
extern "C" void kernel_launch(void* const* d_in, const int* in_sizes, int n_in,
                              void* d_out, int out_size, void* d_ws, size_t ws_size,
                              hipStream_t stream) {
  const float* x  = (const float*)d_in[0];
  const float* Wq = (const float*)d_in[1];
  const float* Wk = (const float*)d_in[2];
  const float* Wv = (const float*)d_in[3];
  float* out = (float*)d_out;

  // ws layout (f16 elems): xb 8M | Wh 3M | Qh 8M | Kh 8M | VT 8M ([1024][8192]) |
  //                        Sc 16M f16 scores->probs in place (4 x 2048 x 2048)
  if (ws_size < (size_t)51 * 1024 * 1024 * 2) return;

  f16* xb = (f16*)d_ws;
  f16* Wh = xb + (size_t)8 * 1024 * 1024;
  f16* Qh = Wh + (size_t)3 * 1024 * 1024;
  f16* Kh = Qh + (size_t)8 * 1024 * 1024;
  f16* VT = Kh + (size_t)8 * 1024 * 1024;
  f16* Sc = VT + (size_t)8 * 1024 * 1024;

  const long QOFF = (long)SEQ * DIM;  // per-batch Q/K offset
  const long SOFF = (long)SEQ * SEQ;  // per-batch score offset (f16 elems)

  cvt_all<<<11264, 256, 0, stream>>>(x, Wq, Wk, Wv, xb, Wh);

  // Fused QKV: M=8192, N=3072 (Wq|Wk|Wv in Wh), K=1024.
  gemm_bt<3, 0><<<dim3(64, 24, 1), 256, 0, stream>>>(xb, DIM, 0, Wh, DIM, 0, Qh, 0, 0, DIM);

  // scores = Q K^T (causal block-skip), f16 out
  gemm_bt<1, 1><<<dim3(16, 16, 4), 256, 0, stream>>>(Qh, DIM, QOFF, Kh, DIM, QOFF,
                                                     Sc, SEQ, SOFF, DIM);

  // causal softmax (scale 1/32), in-place f16 probs, zero above diagonal
  softmax_causal<<<dim3(SEQ, BATCH), 256, 0, stream>>>(Sc);

  // Z = P V  (A = probs f16 ld 2048; B = VT ld 8192; per-M-tile K-limit)
  gemm_bt<0, 2><<<dim3(16, 8, 4), 256, 0, stream>>>(Sc, SEQ, SOFF,
                                                    VT, BATCH * SEQ, SEQ,
                                                    out, DIM, (long)SEQ * DIM, SEQ);
}

// Round 5
// 253.042 us; speedup vs baseline: 1.4859x; 1.4859x over previous
//
#include <hip/hip_runtime.h>
#include <stdint.h>
#include <math.h>

#define SEQ   2048
#define DIM   1024
#define BATCH 4

typedef _Float16 f16;
typedef __attribute__((ext_vector_type(8))) _Float16 f16x8;
typedef __attribute__((ext_vector_type(4))) _Float16 f16x4;
typedef __attribute__((ext_vector_type(4))) float   f32x4;

typedef void __attribute__((address_space(1))) vg_t;
typedef void __attribute__((address_space(3))) vl_t;

__device__ __forceinline__ void gld16(const void* g, void* l) {
  // async global->LDS, 16B per lane; LDS dest = wave-uniform base + lane*16
  __builtin_amdgcn_global_load_lds((vg_t*)g, (vl_t*)l, 16, 0, 0);
}

// ---------------------------------------------------------------------------
// Fused fp32->fp16 convert of x, Wq, Wk, Wv in ONE dispatch.
// ---------------------------------------------------------------------------
__global__ __launch_bounds__(256) void cvt_all(const float* __restrict__ x,
                                               const float* __restrict__ wq,
                                               const float* __restrict__ wk,
                                               const float* __restrict__ wv,
                                               f16* __restrict__ xb,
                                               f16* __restrict__ wh) {
  const int bx = blockIdx.x;
  const float* in; f16* out; int base;
  if (bx < 8192)       { in = x;  out = xb;             base = bx; }
  else if (bx < 9216)  { in = wq; out = wh;             base = bx - 8192; }
  else if (bx < 10240) { in = wk; out = wh + (1 << 20); base = bx - 9216; }
  else                 { in = wv; out = wh + (2 << 20); base = bx - 10240; }
  const long i = ((long)base * 256 + threadIdx.x) * 4;
  float4 v = *(const float4*)(in + i);
  f16x4 o = { (f16)v.x, (f16)v.y, (f16)v.z, (f16)v.w };
  *(f16x4*)(out + i) = o;
}

// ---------------------------------------------------------------------------
// NT GEMM: C[m,n] = sum_k A[m,k]*B[n,k], fp16 in, fp32 acc.
// 128x128 tile, 4 waves (2x2 of 64x64), 16x16x32 MFMA.
// BK: 64 or 128. DBUF: 0 = single-buffer 2-barrier K-loop (R2, measured best
// for scores/PV @BK128); 1 = double-buffer 1-barrier (R3, measured best for
// QKV @BK64: 73 vs 80 us).
// MODE: 0 fp32 row-major C | 1 f16 row-major C | 2 f16 transposed C |
//       3 fused QKV routing (Q,K row-major + V transposed)
// CAUSAL: 0 none
//         2 PV: K-limit m0+128, m0 REVERSED (longest blocks dispatch first)
//         3 scores: COMPACT triangular grid, 1D blockIdx = z*136 + tri(x,y)
// XOR chunk swizzle: LDS slot (row,j) holds global 16B chunk j ^ (row&(CH-1)).
// ---------------------------------------------------------------------------
template <int MODE, int CAUSAL, int BK, int DBUF>
__global__ __launch_bounds__(256) void gemm_bt(const f16* __restrict__ A, int lda, long aOffZ,
                                               const f16* __restrict__ B, int ldb, long bOffZ,
                                               void* __restrict__ Cv, int ldc, long cOffZ,
                                               int K) {
  constexpr int CH  = BK / 8;    // 16B chunks per row
  constexpr int RPL = 64 / CH;   // rows per wave-load
  constexpr int NL  = 32 / RPL;  // wave-loads per tile per wave
  constexpr int NB  = DBUF ? 2 : 1;
  __shared__ __align__(16) f16 lA[NB][128 * BK];
  __shared__ __align__(16) f16 lB[NB][128 * BK];

  const int tid  = threadIdx.x;
  const int wave = tid >> 6;
  const int lane = tid & 63;

  int m0, n0, z;
  if constexpr (CAUSAL == 3) {
    // compact lower-triangle: t2 -> (x,y), y <= x, 136 tiles/batch
    const int bx = blockIdx.x;
    z = bx / 136;
    const int t2 = bx - z * 136;
    int x = (int)((sqrtf(8.0f * (float)t2 + 1.0f) - 1.0f) * 0.5f);
    while ((x + 1) * (x + 2) / 2 <= t2) ++x;
    while (x * (x + 1) / 2 > t2) --x;
    const int y = t2 - x * (x + 1) / 2;
    m0 = x * 128; n0 = y * 128;
  } else if constexpr (CAUSAL == 2) {
    m0 = (int)(gridDim.x - 1 - blockIdx.x) * 128;  // long blocks first
    n0 = blockIdx.y * 128;
    z  = blockIdx.z;
  } else {
    m0 = blockIdx.x * 128;
    n0 = blockIdx.y * 128;
    z  = blockIdx.z;
  }
  const int Keff = (CAUSAL == 2) ? (m0 + 128) : K;

  const f16* Ab = A + (long)z * aOffZ + (long)m0 * lda;
  const f16* Bb = B + (long)z * bOffZ + (long)n0 * ldb;

  const int wm = (wave & 1) * 64;
  const int wn = (wave >> 1) * 64;

  f32x4 acc[4][4] = {};

  const int srow = lane / CH;   // staging: row within group
  const int sj   = lane % CH;   // staging: 16B chunk in row
  const int fr   = lane & 15;   // fragment row
  const int fq   = lane >> 4;   // fragment quad

  auto stage = [&](int buf, int kt) {
#pragma unroll
    for (int j = 0; j < NL; ++j) {
      const int rgrp = j * 4 + wave;
      const int row  = rgrp * RPL + srow;
      const int gch  = sj ^ (row & (CH - 1));
      gld16(Ab + (long)row * lda + kt + gch * 8, (void*)(&lA[buf][rgrp * 512 + lane * 8]));
      gld16(Bb + (long)row * ldb + kt + gch * 8, (void*)(&lB[buf][rgrp * 512 + lane * 8]));
    }
  };

  auto compute = [&](int buf) {
#pragma unroll
    for (int kk = 0; kk < BK; kk += 32) {
      f16x8 af[4], bf[4];
#pragma unroll
      for (int i = 0; i < 4; ++i) {
        const int arow = wm + i * 16 + fr;
        const int ach  = (kk / 8 + fq) ^ (arow & (CH - 1));
        af[i] = *(const f16x8*)(&lA[buf][arow * BK + ach * 8]);
        const int brow = wn + i * 16 + fr;
        const int bch  = (kk / 8 + fq) ^ (brow & (CH - 1));
        bf[i] = *(const f16x8*)(&lB[buf][brow * BK + bch * 8]);
      }
#pragma unroll
      for (int mi = 0; mi < 4; ++mi)
#pragma unroll
        for (int ni = 0; ni < 4; ++ni)
          acc[mi][ni] = __builtin_amdgcn_mfma_f32_16x16x32_f16(af[mi], bf[ni], acc[mi][ni], 0, 0, 0);
    }
  };

  if constexpr (DBUF) {
    stage(0, 0);
    for (int kt = 0; kt < Keff; kt += 2 * BK) {
      __syncthreads();
      if (kt + BK < Keff) stage(1, kt + BK);
      compute(0);
      if (kt + BK < Keff) {
        __syncthreads();
        if (kt + 2 * BK < Keff) stage(0, kt + 2 * BK);
        compute(1);
      }
    }
  } else {
    for (int kt = 0; kt < Keff; kt += BK) {
      __syncthreads();
      stage(0, kt);
      __syncthreads();
      compute(0);
    }
  }

  // Epilogue. C/D layout: col = lane&15, row = (lane>>4)*4 + reg
#pragma unroll
  for (int mi = 0; mi < 4; ++mi) {
    const int row = m0 + wm + mi * 16 + fq * 4;
#pragma unroll
    for (int ni = 0; ni < 4; ++ni) {
      const int col = n0 + wn + ni * 16 + fr;
      if constexpr (MODE == 0) {
        float* C = (float*)Cv + (long)z * cOffZ;
#pragma unroll
        for (int r = 0; r < 4; ++r) C[(long)(row + r) * ldc + col] = acc[mi][ni][r];
      } else if constexpr (MODE == 1) {
        f16* C = (f16*)Cv + (long)z * cOffZ;
#pragma unroll
        for (int r = 0; r < 4; ++r) C[(long)(row + r) * ldc + col] = (f16)acc[mi][ni][r];
      } else if constexpr (MODE == 2) {
        f16* C = (f16*)Cv + (long)z * cOffZ;
        f16x4 o = { (f16)acc[mi][ni][0], (f16)acc[mi][ni][1],
                    (f16)acc[mi][ni][2], (f16)acc[mi][ni][3] };
        *(f16x4*)(C + (long)col * ldc + row) = o;
      } else {  // MODE 3: fused QKV routing (wave-uniform; tiles don't straddle 1024-boundaries)
        f16* Qh  = (f16*)Cv;
        f16* Kh  = Qh + (size_t)8 * 1024 * 1024;
        f16* VTb = Kh + (size_t)8 * 1024 * 1024;
        if (col < 1024) {
#pragma unroll
          for (int r = 0; r < 4; ++r) Qh[(long)(row + r) * DIM + col] = (f16)acc[mi][ni][r];
        } else if (col < 2048) {
#pragma unroll
          for (int r = 0; r < 4; ++r) Kh[(long)(row + r) * DIM + (col - 1024)] = (f16)acc[mi][ni][r];
        } else {
          f16x4 o = { (f16)acc[mi][ni][0], (f16)acc[mi][ni][1],
                      (f16)acc[mi][ni][2], (f16)acc[mi][ni][3] };
          *(f16x4*)(VTb + (long)(col - 2048) * (BATCH * SEQ) + row) = o;
        }
      }
    }
  }
}

// ---------------------------------------------------------------------------
// Causal softmax over f16 score rows, in-place (zero above diagonal).
// grid = (SEQ, BATCH), block = 256, 8 contiguous elems/thread (f16x8).
// ---------------------------------------------------------------------------
__global__ __launch_bounds__(256) void softmax_causal(f16* S) {
  const int q = blockIdx.x, b = blockIdx.y;
  f16* row = S + ((long)b * SEQ + q) * SEQ;
  const int tid = threadIdx.x;
  const int lane = tid & 63, wave = tid >> 6;
  const int nvalid = q + 1;

  f16x8 vv = *(const f16x8*)(row + tid * 8);
  float v[8];
  float m = -3.0e38f;
#pragma unroll
  for (int i = 0; i < 8; ++i) {
    const int k = tid * 8 + i;
    v[i] = (k < nvalid) ? (float)vv[i] * 0.03125f : -3.0e38f;
    m = fmaxf(m, v[i]);
  }
#pragma unroll
  for (int off = 32; off; off >>= 1) m = fmaxf(m, __shfl_xor(m, off));
  __shared__ float redm[4], reds[4];
  if (lane == 0) redm[wave] = m;
  __syncthreads();  // all reads of `row` complete before this point
  m = fmaxf(fmaxf(redm[0], redm[1]), fmaxf(redm[2], redm[3]));

  float s = 0.f;
#pragma unroll
  for (int i = 0; i < 8; ++i) {
    const float p = (v[i] > -1.0e37f) ? __expf(v[i] - m) : 0.f;
    v[i] = p;
    s += p;
  }
#pragma unroll
  for (int off = 32; off; off >>= 1) s += __shfl_xor(s, off);
  if (lane == 0) reds[wave] = s;
  __syncthreads();
  s = reds[0] + reds[1] + reds[2] + reds[3];
  const float inv = 1.f / s;
  f16x8 o;
#pragma unroll
  for (int i = 0; i < 8; ++i) o[i] = (f16)(v[i] * inv);
  *(f16x8*)(row + tid * 8) = o;  // after barriers -> no overlap hazard
}

// ---------------------------------------------------------------------------
extern "C" void kernel_launch(void* const* d_in, const int* in_sizes, int n_in,
                              void* d_out, int out_size, void* d_ws, size_t ws_size,
                              hipStream_t stream) {
  const float* x  = (const float*)d_in[0];
  const float* Wq = (const float*)d_in[1];
  const float* Wk = (const float*)d_in[2];
  const float* Wv = (const float*)d_in[3];
  float* out = (float*)d_out;

  // ws layout (f16 elems): xb 8M | Wh 3M | Qh 8M | Kh 8M | VT 8M ([1024][8192]) |
  //                        Sc 16M f16 scores->probs in place (4 x 2048 x 2048)
  if (ws_size < (size_t)51 * 1024 * 1024 * 2) return;

  f16* xb = (f16*)d_ws;
  f16* Wh = xb + (size_t)8 * 1024 * 1024;
  f16* Qh = Wh + (size_t)3 * 1024 * 1024;
  f16* Kh = Qh + (size_t)8 * 1024 * 1024;
  f16* VT = Kh + (size_t)8 * 1024 * 1024;
  f16* Sc = VT + (size_t)8 * 1024 * 1024;

  const long QOFF = (long)SEQ * DIM;  // per-batch Q/K offset
  const long SOFF = (long)SEQ * SEQ;  // per-batch score offset (f16 elems)

  cvt_all<<<11264, 256, 0, stream>>>(x, Wq, Wk, Wv, xb, Wh);

  // Fused QKV: M=8192, N=3072, K=1024. DBUF BK=64 (R3-measured 73 us).
  gemm_bt<3, 0, 64, 1><<<dim3(64, 24, 1), 256, 0, stream>>>(xb, DIM, 0, Wh, DIM, 0,
                                                            Qh, 0, 0, DIM);

  // scores = Q K^T, compact triangular grid (136 tiles/batch, no dead blocks),
  // f16 out, single-buf BK=128 (R2-measured best).
  gemm_bt<1, 3, 128, 0><<<dim3(136 * BATCH, 1, 1), 256, 0, stream>>>(Qh, DIM, QOFF,
                                                                     Kh, DIM, QOFF,
                                                                     Sc, SEQ, SOFF, DIM);

  // causal softmax (scale 1/32), in-place f16 probs, zero above diagonal
  softmax_causal<<<dim3(SEQ, BATCH), 256, 0, stream>>>(Sc);

  // Z = P V, single-buf BK=128, per-M-tile K-limit, LONGEST blocks first.
  gemm_bt<0, 2, 128, 0><<<dim3(16, 8, 4), 256, 0, stream>>>(Sc, SEQ, SOFF,
                                                            VT, BATCH * SEQ, SEQ,
                                                            out, DIM, (long)SEQ * DIM, SEQ);
}

// Round 6
// 251.113 us; speedup vs baseline: 1.4973x; 1.0077x over previous
//
#include <hip/hip_runtime.h>
#include <stdint.h>

#define SEQ   2048
#define DIM   1024
#define BATCH 4

typedef _Float16 f16;
typedef __attribute__((ext_vector_type(8))) _Float16 f16x8;
typedef __attribute__((ext_vector_type(4))) _Float16 f16x4;
typedef __attribute__((ext_vector_type(4))) float   f32x4;

typedef void __attribute__((address_space(1))) vg_t;
typedef void __attribute__((address_space(3))) vl_t;

__device__ __forceinline__ void gld16(const void* g, void* l) {
  // async global->LDS, 16B per lane; LDS dest = wave-uniform base + lane*16
  __builtin_amdgcn_global_load_lds((vg_t*)g, (vl_t*)l, 16, 0, 0);
}

// ---------------------------------------------------------------------------
// Fused fp32->fp16 convert of x, Wq, Wk, Wv in ONE dispatch.
// ---------------------------------------------------------------------------
__global__ __launch_bounds__(256) void cvt_all(const float* __restrict__ x,
                                               const float* __restrict__ wq,
                                               const float* __restrict__ wk,
                                               const float* __restrict__ wv,
                                               f16* __restrict__ xb,
                                               f16* __restrict__ wh) {
  const int bx = blockIdx.x;
  const float* in; f16* out; int base;
  if (bx < 8192)       { in = x;  out = xb;             base = bx; }
  else if (bx < 9216)  { in = wq; out = wh;             base = bx - 8192; }
  else if (bx < 10240) { in = wk; out = wh + (1 << 20); base = bx - 9216; }
  else                 { in = wv; out = wh + (2 << 20); base = bx - 10240; }
  const long i = ((long)base * 256 + threadIdx.x) * 4;
  float4 v = *(const float4*)(in + i);
  f16x4 o = { (f16)v.x, (f16)v.y, (f16)v.z, (f16)v.w };
  *(f16x4*)(out + i) = o;
}

// ---------------------------------------------------------------------------
// NT GEMM: C[m,n] = sum_k A[m,k]*B[n,k], fp16 in, fp32 acc.
// *** 256x128 block tile, 2x2 waves of 128x64 each (acc 8x4 f32x4) ***
// Rationale: LDS bytes/FLOP drops 0.047 -> 0.035 vs 128x128/64x64, lifting
// the LDS-pipe ceiling on MfmaUtil (the measured ~30% plateau R1-R5).
// BK=64, single-buffer, 2 barriers/K-step (measured best structure, R2).
// LDS 48 KB -> 2 blocks/CU; __launch_bounds__(256,2) caps VGPR at 256.
// MODE: 0 fp32 row-major C | 1 f16 row-major C |
//       3 fused QKV routing (Q,K row-major + V transposed [p][B*S])
// CAUSAL: 0 none | 1 skip tiles fully above diagonal (scores) |
//         2 K-limit m0+256 (PV)
// XOR chunk swizzle: LDS slot (row,j) holds global 16B chunk j ^ (row&7).
// ---------------------------------------------------------------------------
template <int MODE, int CAUSAL>
__global__ __launch_bounds__(256, 2) void gemm_bt(const f16* __restrict__ A, int lda, long aOffZ,
                                                  const f16* __restrict__ B, int ldb, long bOffZ,
                                                  void* __restrict__ Cv, int ldc, long cOffZ,
                                                  int K) {
  constexpr int BK = 64;
  __shared__ __align__(16) f16 lA[256 * BK];   // 32 KB
  __shared__ __align__(16) f16 lB[128 * BK];   // 16 KB

  const int tid  = threadIdx.x;
  const int wave = tid >> 6;
  const int lane = tid & 63;
  const int m0 = blockIdx.x * 256;
  const int n0 = blockIdx.y * 128;
  const int z  = blockIdx.z;

  if (CAUSAL == 1 && n0 >= m0 + 256) return;   // tile fully above causal diagonal
  const int Keff = (CAUSAL == 2) ? (m0 + 256) : K;

  const f16* Ab = A + (long)z * aOffZ + (long)m0 * lda;
  const f16* Bb = B + (long)z * bOffZ + (long)n0 * ldb;

  const int wm = (wave & 1) * 128;   // wave M-offset (128-row wave tile)
  const int wn = (wave >> 1) * 64;   // wave N-offset (64-col wave tile)

  f32x4 acc[8][4] = {};

  const int srow = lane >> 3;   // staging: row within 8-row group
  const int sj   = lane & 7;    // staging: 16B chunk in row
  const int fr   = lane & 15;   // fragment row
  const int fq   = lane >> 4;   // fragment quad

  for (int kt = 0; kt < Keff; kt += BK) {
    __syncthreads();  // previous iteration's ds_reads done
#pragma unroll
    for (int j = 0; j < 8; ++j) {            // A: 256 rows, 32 KB
      const int rgrp = j * 4 + wave;         // 0..31
      const int row  = rgrp * 8 + srow;      // 0..255
      const int gch  = sj ^ (row & 7);
      gld16(Ab + (long)row * lda + kt + gch * 8, (void*)(lA + rgrp * 512 + lane * 8));
    }
#pragma unroll
    for (int j = 0; j < 4; ++j) {            // B: 128 rows, 16 KB
      const int rgrp = j * 4 + wave;         // 0..15
      const int row  = rgrp * 8 + srow;      // 0..127
      const int gch  = sj ^ (row & 7);
      gld16(Bb + (long)row * ldb + kt + gch * 8, (void*)(lB + rgrp * 512 + lane * 8));
    }
    __syncthreads();  // vmcnt drained -> staging visible

#pragma unroll
    for (int kk = 0; kk < BK; kk += 32) {
      f16x8 af[8], bf[4];
#pragma unroll
      for (int i = 0; i < 8; ++i) {
        const int arow = wm + i * 16 + fr;
        const int ach  = (kk / 8 + fq) ^ (arow & 7);
        af[i] = *(const f16x8*)(lA + arow * BK + ach * 8);
      }
#pragma unroll
      for (int j = 0; j < 4; ++j) {
        const int brow = wn + j * 16 + fr;
        const int bch  = (kk / 8 + fq) ^ (brow & 7);
        bf[j] = *(const f16x8*)(lB + brow * BK + bch * 8);
      }
#pragma unroll
      for (int mi = 0; mi < 8; ++mi)
#pragma unroll
        for (int ni = 0; ni < 4; ++ni)
          acc[mi][ni] = __builtin_amdgcn_mfma_f32_16x16x32_f16(af[mi], bf[ni], acc[mi][ni], 0, 0, 0);
    }
  }

  // Epilogue. C/D layout: col = lane&15, row = (lane>>4)*4 + reg
#pragma unroll
  for (int mi = 0; mi < 8; ++mi) {
    const int row = m0 + wm + mi * 16 + fq * 4;
#pragma unroll
    for (int ni = 0; ni < 4; ++ni) {
      const int col = n0 + wn + ni * 16 + fr;
      if constexpr (MODE == 0) {
        float* C = (float*)Cv + (long)z * cOffZ;
#pragma unroll
        for (int r = 0; r < 4; ++r) C[(long)(row + r) * ldc + col] = acc[mi][ni][r];
      } else if constexpr (MODE == 1) {
        f16* C = (f16*)Cv + (long)z * cOffZ;
#pragma unroll
        for (int r = 0; r < 4; ++r) C[(long)(row + r) * ldc + col] = (f16)acc[mi][ni][r];
      } else {  // MODE 3: fused QKV routing (wave-uniform; 128-col tiles never straddle 1024-boundaries)
        f16* Qh  = (f16*)Cv;
        f16* Kh  = Qh + (size_t)8 * 1024 * 1024;
        f16* VTb = Kh + (size_t)8 * 1024 * 1024;
        if (col < 1024) {
#pragma unroll
          for (int r = 0; r < 4; ++r) Qh[(long)(row + r) * DIM + col] = (f16)acc[mi][ni][r];
        } else if (col < 2048) {
#pragma unroll
          for (int r = 0; r < 4; ++r) Kh[(long)(row + r) * DIM + (col - 1024)] = (f16)acc[mi][ni][r];
        } else {
          f16x4 o = { (f16)acc[mi][ni][0], (f16)acc[mi][ni][1],
                      (f16)acc[mi][ni][2], (f16)acc[mi][ni][3] };
          *(f16x4*)(VTb + (long)(col - 2048) * (BATCH * SEQ) + row) = o;
        }
      }
    }
  }
}

// ---------------------------------------------------------------------------
// Causal softmax over f16 score rows, in-place (zero above diagonal).
// grid = (SEQ, BATCH), block = 256, 8 contiguous elems/thread (f16x8).
// ---------------------------------------------------------------------------
__global__ __launch_bounds__(256) void softmax_causal(f16* S) {
  const int q = blockIdx.x, b = blockIdx.y;
  f16* row = S + ((long)b * SEQ + q) * SEQ;
  const int tid = threadIdx.x;
  const int lane = tid & 63, wave = tid >> 6;
  const int nvalid = q + 1;

  f16x8 vv = *(const f16x8*)(row + tid * 8);
  float v[8];
  float m = -3.0e38f;
#pragma unroll
  for (int i = 0; i < 8; ++i) {
    const int k = tid * 8 + i;
    v[i] = (k < nvalid) ? (float)vv[i] * 0.03125f : -3.0e38f;
    m = fmaxf(m, v[i]);
  }
#pragma unroll
  for (int off = 32; off; off >>= 1) m = fmaxf(m, __shfl_xor(m, off));
  __shared__ float redm[4], reds[4];
  if (lane == 0) redm[wave] = m;
  __syncthreads();  // all reads of `row` complete before this point
  m = fmaxf(fmaxf(redm[0], redm[1]), fmaxf(redm[2], redm[3]));

  float s = 0.f;
#pragma unroll
  for (int i = 0; i < 8; ++i) {
    const float p = (v[i] > -1.0e37f) ? __expf(v[i] - m) : 0.f;
    v[i] = p;
    s += p;
  }
#pragma unroll
  for (int off = 32; off; off >>= 1) s += __shfl_xor(s, off);
  if (lane == 0) reds[wave] = s;
  __syncthreads();
  s = reds[0] + reds[1] + reds[2] + reds[3];
  const float inv = 1.f / s;
  f16x8 o;
#pragma unroll
  for (int i = 0; i < 8; ++i) o[i] = (f16)(v[i] * inv);
  *(f16x8*)(row + tid * 8) = o;  // after barriers -> no overlap hazard
}

// ---------------------------------------------------------------------------
extern "C" void kernel_launch(void* const* d_in, const int* in_sizes, int n_in,
                              void* d_out, int out_size, void* d_ws, size_t ws_size,
                              hipStream_t stream) {
  const float* x  = (const float*)d_in[0];
  const float* Wq = (const float*)d_in[1];
  const float* Wk = (const float*)d_in[2];
  const float* Wv = (const float*)d_in[3];
  float* out = (float*)d_out;

  // ws layout (f16 elems): xb 8M | Wh 3M | Qh 8M | Kh 8M | VT 8M ([1024][8192]) |
  //                        Sc 16M f16 scores->probs in place (4 x 2048 x 2048)
  if (ws_size < (size_t)51 * 1024 * 1024 * 2) return;

  f16* xb = (f16*)d_ws;
  f16* Wh = xb + (size_t)8 * 1024 * 1024;
  f16* Qh = Wh + (size_t)3 * 1024 * 1024;
  f16* Kh = Qh + (size_t)8 * 1024 * 1024;
  f16* VT = Kh + (size_t)8 * 1024 * 1024;
  f16* Sc = VT + (size_t)8 * 1024 * 1024;

  const long QOFF = (long)SEQ * DIM;  // per-batch Q/K offset
  const long SOFF = (long)SEQ * SEQ;  // per-batch score offset (f16 elems)

  cvt_all<<<11264, 256, 0, stream>>>(x, Wq, Wk, Wv, xb, Wh);

  // Fused QKV: M=8192 (32 tiles of 256), N=3072 (24 tiles of 128), K=1024.
  gemm_bt<3, 0><<<dim3(32, 24, 1), 256, 0, stream>>>(xb, DIM, 0, Wh, DIM, 0,
                                                     Qh, 0, 0, DIM);

  // scores = Q K^T, rect grid + causal tile skip (288 live of 512), f16 out.
  gemm_bt<1, 1><<<dim3(8, 16, 4), 256, 0, stream>>>(Qh, DIM, QOFF, Kh, DIM, QOFF,
                                                    Sc, SEQ, SOFF, DIM);

  // causal softmax (scale 1/32), in-place f16 probs, zero above diagonal
  softmax_causal<<<dim3(SEQ, BATCH), 256, 0, stream>>>(Sc);

  // Z = P V: 256 blocks (exactly 1/CU), per-M-tile K-limit m0+256.
  gemm_bt<0, 2><<<dim3(8, 8, 4), 256, 0, stream>>>(Sc, SEQ, SOFF,
                                                   VT, BATCH * SEQ, SEQ,
                                                   out, DIM, (long)SEQ * DIM, SEQ);
}